// Round 1
// 878.455 us; speedup vs baseline: 1.1783x; 1.1783x over previous
//
#include <hip/hip_runtime.h>

#define NUM_USERS_C 500000
#define EPS_F 1e-12f

// ---------------------------------------------------------------------------
// Pass 1 over edges: self-loop flags + per-dest count. The counting atomic's
// return value IS the CSR slot -> store it so scatter needs no atomics.
// ---------------------------------------------------------------------------
__global__ void k_edgeprep(const int* __restrict__ row, const int* __restrict__ col,
                           int* __restrict__ flags, int* __restrict__ cnt,
                           int* __restrict__ slot, int E) {
    int e = blockIdx.x * blockDim.x + threadIdx.x;
    if (e < E) {
        int r = row[e], c = col[e];
        if (r == c) flags[r] = 1;          // benign race, all store 1
        slot[e] = atomicAdd(&cnt[c], 1);   // slot within dest node's CSR row
    }
}

// ---------------------------------------------------------------------------
// Two-level exclusive scan: cnt[0..N) -> rowptr[0..N]
// ---------------------------------------------------------------------------
__global__ __launch_bounds__(256) void k_blocksum(const int* __restrict__ cnt,
                                                  int* __restrict__ bsum, int N) {
    __shared__ int s[256];
    int i = blockIdx.x * 256 + threadIdx.x;
    s[threadIdx.x] = (i < N) ? cnt[i] : 0;
    __syncthreads();
    for (int d = 128; d > 0; d >>= 1) {
        if (threadIdx.x < d) s[threadIdx.x] += s[threadIdx.x + d];
        __syncthreads();
    }
    if (threadIdx.x == 0) bsum[blockIdx.x] = s[0];
}

// Single block: exclusive scan of NB (<=1024) block sums; also writes rowptr[N].
__global__ __launch_bounds__(1024) void k_scanbsum(const int* __restrict__ bsum,
                                                   int* __restrict__ boff,
                                                   int* __restrict__ rowptr,
                                                   int NB, int N) {
    __shared__ int s[1024];
    int t = threadIdx.x;
    int v = (t < NB) ? bsum[t] : 0;
    s[t] = v;
    __syncthreads();
    for (int d = 1; d < 1024; d <<= 1) {
        int u = (t >= d) ? s[t - d] : 0;
        __syncthreads();
        s[t] += u;
        __syncthreads();
    }
    if (t < NB) boff[t] = s[t] - v;       // exclusive prefix of block sums
    if (t == 1023) rowptr[N] = s[1023];   // grand total
}

__global__ __launch_bounds__(256) void k_rowptr(const int* __restrict__ cnt,
                                                const int* __restrict__ boff,
                                                int* __restrict__ rowptr, int N) {
    __shared__ int s[256];
    int i = blockIdx.x * 256 + threadIdx.x;
    int v = (i < N) ? cnt[i] : 0;
    s[threadIdx.x] = v;
    __syncthreads();
    for (int d = 1; d < 256; d <<= 1) {
        int u = (threadIdx.x >= d) ? s[threadIdx.x - d] : 0;
        __syncthreads();
        s[threadIdx.x] += u;
        __syncthreads();
    }
    if (i < N) rowptr[i] = boff[blockIdx.x] + s[threadIdx.x] - v;  // exclusive
}

// Scatter edges into CSR order (atomic-free): emeta[pos] = {src_row, raw_w}
__global__ void k_scatter(const int* __restrict__ row, const int* __restrict__ col,
                          const float* __restrict__ w, const int* __restrict__ slot,
                          const int* __restrict__ rowptr,
                          int2* __restrict__ emeta, int E) {
    int e = blockIdx.x * blockDim.x + threadIdx.x;
    if (e < E) {
        int c = col[e];
        int pos = rowptr[c] + slot[e];
        emeta[pos] = make_int2(row[e], __float_as_int(w[e]));
    }
}

// Weighted degree from CSR (coalesced, atomic-free) -> dinfo = {dinv, loop_w}
__global__ __launch_bounds__(256) void k_deg(const int* __restrict__ rowptr,
                                             const int2* __restrict__ emeta,
                                             const int* __restrict__ flags,
                                             float2* __restrict__ dinfo, int N) {
    int lane = threadIdx.x & 63;
    int node = blockIdx.x * 4 + (threadIdx.x >> 6);
    if (node >= N) return;
    int beg = rowptr[node], end = rowptr[node + 1];
    float s = 0.0f;
    for (int i = beg + lane; i < end; i += 64)
        s += __int_as_float(emeta[i].y);
    #pragma unroll
    for (int off = 32; off > 0; off >>= 1) s += __shfl_xor(s, off, 64);
    float lw = flags[node] ? 0.0f : 1.0f;
    float d = s + lw;
    float di = (d > 0.0f) ? rsqrtf(fmaxf(d, EPS_F)) : 0.0f;
    if (lane == 0) dinfo[node] = make_float2(di, lw);
}

// ---------------------------------------------------------------------------
// Node features: one wave per node, lane = dim. Item matvec uses readlane
// (VALU broadcast, no LDS/shfl traffic) + 4-way split accumulator.
// Writes acc = x0 and xt = dinv * x0 (the propagated state).
// ---------------------------------------------------------------------------
__global__ __launch_bounds__(256) void k_features(
    const int* __restrict__ batch_nodes,
    const float* __restrict__ user_emb, const float* __restrict__ artist_emb,
    const float* __restrict__ album_emb, const float* __restrict__ audio_emb,
    const int* __restrict__ artist_ids, const int* __restrict__ album_ids,
    const float* __restrict__ proj_w, const float* __restrict__ proj_b,
    const float2* __restrict__ dinfo,
    float* __restrict__ xt, float* __restrict__ acc, int N)
{
    __shared__ float Ws[128 * 64];
    for (int i = threadIdx.x; i < 128 * 64; i += blockDim.x)
        Ws[i] = proj_w[i];
    __syncthreads();

    const int lane = threadIdx.x & 63;
    const int wid = threadIdx.x >> 6;
    const int wavesPerBlock = blockDim.x >> 6;
    const int waveStride = gridDim.x * wavesPerBlock;
    const float bias = proj_b[lane];

    for (int n = blockIdx.x * wavesPerBlock + wid; n < N; n += waveStride) {
        int idx = batch_nodes[n];
        float val;
        if (idx < NUM_USERS_C) {
            val = user_emb[(size_t)idx * 64 + lane];
        } else {
            int it = idx - NUM_USERS_C;
            int aid = artist_ids[it];
            int bid = album_ids[it];
            float vlo = audio_emb[(size_t)it * 64 + lane];
            float vhi = 0.5f * (artist_emb[(size_t)aid * 64 + lane] +
                                album_emb[(size_t)bid * 64 + lane]);
            int ilo = __float_as_int(vlo);
            int ihi = __float_as_int(vhi);
            float s0 = bias, s1 = 0.0f, s2 = 0.0f, s3 = 0.0f;
            #pragma unroll
            for (int k = 0; k < 64; k += 4) {
                float a0 = __int_as_float(__builtin_amdgcn_readlane(ilo, k + 0));
                float a1 = __int_as_float(__builtin_amdgcn_readlane(ilo, k + 1));
                float a2 = __int_as_float(__builtin_amdgcn_readlane(ilo, k + 2));
                float a3 = __int_as_float(__builtin_amdgcn_readlane(ilo, k + 3));
                s0 = fmaf(a0, Ws[(k + 0) * 64 + lane], s0);
                s1 = fmaf(a1, Ws[(k + 1) * 64 + lane], s1);
                s2 = fmaf(a2, Ws[(k + 2) * 64 + lane], s2);
                s3 = fmaf(a3, Ws[(k + 3) * 64 + lane], s3);
            }
            #pragma unroll
            for (int k = 0; k < 64; k += 4) {
                float a0 = __int_as_float(__builtin_amdgcn_readlane(ihi, k + 0));
                float a1 = __int_as_float(__builtin_amdgcn_readlane(ihi, k + 1));
                float a2 = __int_as_float(__builtin_amdgcn_readlane(ihi, k + 2));
                float a3 = __int_as_float(__builtin_amdgcn_readlane(ihi, k + 3));
                s0 = fmaf(a0, Ws[(k + 64) * 64 + lane], s0);
                s1 = fmaf(a1, Ws[(k + 65) * 64 + lane], s1);
                s2 = fmaf(a2, Ws[(k + 66) * 64 + lane], s2);
                s3 = fmaf(a3, Ws[(k + 67) * 64 + lane], s3);
            }
            val = (s0 + s1) + (s2 + s3);
        }
        float ss = val * val;
        #pragma unroll
        for (int off = 32; off > 0; off >>= 1) ss += __shfl_xor(ss, off, 64);
        float scale = 1.0f / fmaxf(sqrtf(ss), EPS_F);
        val *= scale;
        float di = dinfo[n].x;
        acc[(size_t)n * 64 + lane] = val;
        xt[(size_t)n * 64 + lane] = di * val;
    }
}

// ---------------------------------------------------------------------------
// CSR propagation over x~ = dinv*x:  t[c] = sum_e w*x~[r] + lw*x~[c]
//   x_next = dinv[c]*t   (added to acc);   x~_next = dinv[c]*x_next
// ---------------------------------------------------------------------------
__device__ __forceinline__ float prop_accum(
    const int* __restrict__ rowptr, const int2* __restrict__ emeta,
    const float* __restrict__ xs, int node, int lane, float lw)
{
    int beg = rowptr[node], end = rowptr[node + 1];
    float a = lw * xs[(size_t)node * 64 + lane];
    for (int base = beg; base < end; base += 64) {
        int chunk = min(64, end - base);
        int2 m = make_int2(0, 0);
        if (lane < chunk) m = emeta[base + lane];   // coalesced 8B/lane
        int j = 0;
        for (; j + 8 <= chunk; j += 8) {
            int r0 = __shfl(m.x, j + 0); float w0 = __int_as_float(__shfl(m.y, j + 0));
            int r1 = __shfl(m.x, j + 1); float w1 = __int_as_float(__shfl(m.y, j + 1));
            int r2 = __shfl(m.x, j + 2); float w2 = __int_as_float(__shfl(m.y, j + 2));
            int r3 = __shfl(m.x, j + 3); float w3 = __int_as_float(__shfl(m.y, j + 3));
            int r4 = __shfl(m.x, j + 4); float w4 = __int_as_float(__shfl(m.y, j + 4));
            int r5 = __shfl(m.x, j + 5); float w5 = __int_as_float(__shfl(m.y, j + 5));
            int r6 = __shfl(m.x, j + 6); float w6 = __int_as_float(__shfl(m.y, j + 6));
            int r7 = __shfl(m.x, j + 7); float w7 = __int_as_float(__shfl(m.y, j + 7));
            float v0 = xs[(size_t)r0 * 64 + lane];
            float v1 = xs[(size_t)r1 * 64 + lane];
            float v2 = xs[(size_t)r2 * 64 + lane];
            float v3 = xs[(size_t)r3 * 64 + lane];
            float v4 = xs[(size_t)r4 * 64 + lane];
            float v5 = xs[(size_t)r5 * 64 + lane];
            float v6 = xs[(size_t)r6 * 64 + lane];
            float v7 = xs[(size_t)r7 * 64 + lane];
            a = fmaf(w0, v0, a); a = fmaf(w1, v1, a);
            a = fmaf(w2, v2, a); a = fmaf(w3, v3, a);
            a = fmaf(w4, v4, a); a = fmaf(w5, v5, a);
            a = fmaf(w6, v6, a); a = fmaf(w7, v7, a);
        }
        for (; j < chunk; j++) {
            int r = __shfl(m.x, j); float wv = __int_as_float(__shfl(m.y, j));
            a = fmaf(wv, xs[(size_t)r * 64 + lane], a);
        }
    }
    return a;
}

__global__ __launch_bounds__(256) void k_prop(
    const int* __restrict__ rowptr, const int2* __restrict__ emeta,
    const float2* __restrict__ dinfo,
    const float* __restrict__ xs, float* __restrict__ xd,
    float* __restrict__ acc, int N)
{
    int lane = threadIdx.x & 63;
    int node = blockIdx.x * 4 + (threadIdx.x >> 6);
    if (node >= N) return;
    float2 dn = dinfo[node];
    float t = prop_accum(rowptr, emeta, xs, node, lane, dn.y);
    float xnext = dn.x * t;                       // actual x_{l+1}
    acc[(size_t)node * 64 + lane] += xnext;
    xd[(size_t)node * 64 + lane] = dn.x * xnext;  // x~_{l+1}
}

// Last layer: fold acc-add, /4, l2norm; write out only.
__global__ __launch_bounds__(256) void k_prop_final(
    const int* __restrict__ rowptr, const int2* __restrict__ emeta,
    const float2* __restrict__ dinfo,
    const float* __restrict__ xs, float* __restrict__ acc_out, int N)
{
    int lane = threadIdx.x & 63;
    int node = blockIdx.x * 4 + (threadIdx.x >> 6);
    if (node >= N) return;
    float2 dn = dinfo[node];
    float t = prop_accum(rowptr, emeta, xs, node, lane, dn.y);
    float xnext = dn.x * t;
    float v = (acc_out[(size_t)node * 64 + lane] + xnext) * 0.25f;
    float ss = v * v;
    #pragma unroll
    for (int off = 32; off > 0; off >>= 1) ss += __shfl_xor(ss, off, 64);
    float scale = 1.0f / fmaxf(sqrtf(ss), EPS_F);
    acc_out[(size_t)node * 64 + lane] = v * scale;
}

// ---------------------------------------------------------------------------
extern "C" void kernel_launch(void* const* d_in, const int* in_sizes, int n_in,
                              void* d_out, int out_size, void* d_ws, size_t ws_size,
                              hipStream_t stream) {
    const int*   batch_nodes = (const int*)d_in[0];
    const int*   edge_index  = (const int*)d_in[1];
    const float* edge_w      = (const float*)d_in[2];
    const float* user_emb    = (const float*)d_in[3];
    const float* artist_emb  = (const float*)d_in[4];
    const float* album_emb   = (const float*)d_in[5];
    const float* audio_emb   = (const float*)d_in[6];
    const int*   artist_ids  = (const int*)d_in[7];
    const int*   album_ids   = (const int*)d_in[8];
    const float* proj_w      = (const float*)d_in[9];
    const float* proj_b      = (const float*)d_in[10];

    const int N = in_sizes[0];
    const int E = in_sizes[2];
    const int* row = edge_index;
    const int* col = edge_index + E;
    float* out = (float*)d_out;   // doubles as acc

    const int NB = (N + 255) / 256;   // blocks for the two-level scan

    // workspace carve-up
    char* ws = (char*)d_ws;
    int*    flags  = (int*)ws;    ws += (size_t)N * sizeof(int);
    int*    cnt    = (int*)ws;    ws += (size_t)N * sizeof(int);
    int*    rowptr = (int*)ws;    ws += (size_t)(N + 1) * sizeof(int);
    int*    bsum   = (int*)ws;    ws += (size_t)NB * sizeof(int);
    int*    boff   = (int*)ws;    ws += (size_t)NB * sizeof(int);
    ws = (char*)(((uintptr_t)ws + 15) & ~(uintptr_t)15);
    float2* dinfo  = (float2*)ws; ws += (size_t)N * sizeof(float2);
    int2*   emeta  = (int2*)ws;   ws += (size_t)E * sizeof(int2);
    float*  xA     = (float*)ws;  ws += (size_t)N * 64 * sizeof(float);
    float*  xB     = (float*)ws;  ws += (size_t)N * 64 * sizeof(float);
    // slot[] is only live until k_scatter; xB is first written by k_prop #1.
    int*    slot   = (int*)xB;

    hipMemsetAsync(flags, 0, (size_t)N * sizeof(int), stream);
    hipMemsetAsync(cnt, 0, (size_t)N * sizeof(int), stream);

    const int TB = 256;

    k_edgeprep<<<(E + TB - 1) / TB, TB, 0, stream>>>(row, col, flags, cnt, slot, E);
    k_blocksum<<<NB, 256, 0, stream>>>(cnt, bsum, N);
    k_scanbsum<<<1, 1024, 0, stream>>>(bsum, boff, rowptr, NB, N);
    k_rowptr<<<NB, 256, 0, stream>>>(cnt, boff, rowptr, N);
    k_scatter<<<(E + TB - 1) / TB, TB, 0, stream>>>(row, col, edge_w, slot,
                                                    rowptr, emeta, E);

    int pblocks = (N + 3) / 4;  // 4 waves (nodes) per 256-thread block
    k_deg<<<pblocks, 256, 0, stream>>>(rowptr, emeta, flags, dinfo, N);

    k_features<<<4096, 256, 0, stream>>>(batch_nodes, user_emb, artist_emb, album_emb,
                                         audio_emb, artist_ids, album_ids, proj_w, proj_b,
                                         dinfo, xA, out, N);

    k_prop<<<pblocks, 256, 0, stream>>>(rowptr, emeta, dinfo, xA, xB, out, N);
    k_prop<<<pblocks, 256, 0, stream>>>(rowptr, emeta, dinfo, xB, xA, out, N);
    k_prop_final<<<pblocks, 256, 0, stream>>>(rowptr, emeta, dinfo, xA, out, N);
}